// Round 1
// baseline (3934.166 us; speedup 1.0000x reference)
//
#include <hip/hip_runtime.h>

#define NC    1000000
#define NPAR  100000
#define DIM   64
#define H     4
#define DQK   8
#define DH    32
#define RPE   9
#define KVDIM 96
#define SCALE 0.35355339059327373f  // DQK^-0.5

// ---------------------------------------------------------------------------
// Kernel A: qp[p][o] = SCALE * (x_parent[p] . wq[:,o] + bq[o])
// thread per (p,o); x_parent row broadcast within 32-thread groups (cache-served)
// ---------------------------------------------------------------------------
__global__ void qproj_kernel(const float* __restrict__ xp,
                             const float* __restrict__ wq,
                             const float* __restrict__ bq,
                             float* __restrict__ qp) {
    int t = blockIdx.x * 256 + threadIdx.x;
    if (t >= NPAR * DH) return;
    int p = t >> 5, o = t & 31;
    const float* xr = xp + (size_t)p * DIM;
    float acc = bq[o];
#pragma unroll
    for (int j = 0; j < DIM; ++j) acc += xr[j] * wq[j * DH + o];
    qp[t] = acc * SCALE;
}

// ---------------------------------------------------------------------------
// Kernel B: fused per-child pass.
//  k = x.wkv[:,:32] + bkv[:32] + ea.wk_rpe + bk_rpe
//  q = qp[index] + ea.wq_rpe + bq_rpe          (SCALE already baked into qp)
//  e_h = exp(sum_d q*k) ; atomicAdd s[p][h] += e_h
//  v_d = x.wkv[:,32+d] + bkv[32+d] ; atomicAdd out[p][d] += e_{d/16} * v_d
// Weights transposed in LDS -> all weight reads are wave-uniform broadcasts.
// ---------------------------------------------------------------------------
__global__ void fused_kernel(const float* __restrict__ xc,
                             const float* __restrict__ ea_g,
                             const int*   __restrict__ index,
                             const float* __restrict__ wkv,
                             const float* __restrict__ bkv,
                             const float* __restrict__ wkr,
                             const float* __restrict__ bkr,
                             const float* __restrict__ wqr,
                             const float* __restrict__ bqr,
                             const float* __restrict__ qp,
                             float* __restrict__ s,
                             float* __restrict__ out) {
    __shared__ float lds[6880];
    float* wkT  = lds;           // [32][64] : wkT[o*64+j] = wkv[j][o]
    float* wvT  = lds + 2048;    // [64][64] : wvT[d*64+j] = wkv[j][32+d]
    float* wkrT = lds + 6144;    // [32][9]
    float* wqrT = lds + 6432;    // [32][9]
    float* bkvL = lds + 6720;    // [96]
    float* bkrL = lds + 6816;    // [32]
    float* bqrL = lds + 6848;    // [32]

    int tid = threadIdx.x;
    for (int i = tid; i < 2048; i += 256) { int o = i >> 6, j = i & 63; wkT[i] = wkv[j * KVDIM + o]; }
    for (int i = tid; i < 4096; i += 256) { int d = i >> 6, j = i & 63; wvT[i] = wkv[j * KVDIM + DH + d]; }
    for (int i = tid; i < 288;  i += 256) { int o = i / 9, r = i - o * 9; wkrT[i] = wkr[r * DH + o]; }
    for (int i = tid; i < 288;  i += 256) { int o = i / 9, r = i - o * 9; wqrT[i] = wqr[r * DH + o]; }
    if (tid < 96) bkvL[tid] = bkv[tid];
    if (tid < 32) { bkrL[tid] = bkr[tid]; bqrL[tid] = bqr[tid]; }
    __syncthreads();

    int c = blockIdx.x * 256 + tid;
    if (c >= NC) return;

    int p = index[c];

    // child row into registers (16 x float4 = 64 VGPRs)
    float4 x4[16];
    const float4* xr = (const float4*)(xc + (size_t)c * DIM);
#pragma unroll
    for (int i = 0; i < 16; ++i) x4[i] = xr[i];

    float ea[RPE];
    const float* er = ea_g + (size_t)c * RPE;
#pragma unroll
    for (int r = 0; r < RPE; ++r) ea[r] = er[r];

    const float* qpr = qp + (size_t)p * DH;
    float ev[H];

    // ---- phase 1: compat + e per head; s accumulation ----
#pragma unroll
    for (int h = 0; h < H; ++h) {
        float compat = 0.f;
#pragma unroll 1
        for (int d = 0; d < DQK; ++d) {
            int o = h * DQK + d;
            float k = bkvL[o] + bkrL[o];
            const float4* wk4 = (const float4*)(wkT + o * 64);
#pragma unroll
            for (int j = 0; j < 16; ++j) {
                float4 w = wk4[j]; float4 xx = x4[j];
                k += xx.x * w.x + xx.y * w.y + xx.z * w.z + xx.w * w.w;
            }
            float q = qpr[o] + bqrL[o];
#pragma unroll
            for (int r = 0; r < RPE; ++r) {
                q += ea[r] * wqrT[o * RPE + r];
                k += ea[r] * wkrT[o * RPE + r];
            }
            compat += q * k;
        }
        ev[h] = __expf(compat);
        atomicAdd(&s[(size_t)p * H + h], ev[h]);
    }

    // ---- phase 2: v projection + weighted scatter ----
    float* outp = out + (size_t)p * DIM;
#pragma unroll
    for (int h = 0; h < H; ++h) {
        float eh = ev[h];
#pragma unroll 1
        for (int dd = 0; dd < 16; ++dd) {
            int d = h * 16 + dd;
            float v = bkvL[DH + d];
            const float4* wv4 = (const float4*)(wvT + d * 64);
#pragma unroll
            for (int j = 0; j < 16; ++j) {
                float4 w = wv4[j]; float4 xx = x4[j];
                v += xx.x * w.x + xx.y * w.y + xx.z * w.z + xx.w * w.w;
            }
            atomicAdd(&outp[d], v * eh);
        }
    }
}

// ---------------------------------------------------------------------------
// Kernel C: out[p][d] /= (s[p][d/16] + 1e-16)
// ---------------------------------------------------------------------------
__global__ void norm_kernel(const float* __restrict__ s, float* __restrict__ out) {
    int t = blockIdx.x * 256 + threadIdx.x;
    if (t >= NPAR * DIM) return;
    int p = t >> 6;
    int h = (t >> 4) & 3;
    out[t] = out[t] / (s[p * H + h] + 1e-16f);
}

extern "C" void kernel_launch(void* const* d_in, const int* in_sizes, int n_in,
                              void* d_out, int out_size, void* d_ws, size_t ws_size,
                              hipStream_t stream) {
    const float* xc   = (const float*)d_in[0];
    const float* xp   = (const float*)d_in[1];
    const int*   idx  = (const int*)d_in[2];
    const float* ea   = (const float*)d_in[3];
    const float* wq   = (const float*)d_in[4];
    const float* bq   = (const float*)d_in[5];
    const float* wkv  = (const float*)d_in[6];
    const float* bkv  = (const float*)d_in[7];
    const float* wkr  = (const float*)d_in[8];
    const float* bkr  = (const float*)d_in[9];
    const float* wqr  = (const float*)d_in[10];
    const float* bqr  = (const float*)d_in[11];
    float* out = (float*)d_out;

    float* qp = (float*)d_ws;                 // NPAR*32 floats
    float* s  = qp + (size_t)NPAR * DH;       // NPAR*4  floats

    hipMemsetAsync(out, 0, (size_t)NPAR * DIM * sizeof(float), stream);
    hipMemsetAsync(s,   0, (size_t)NPAR * H   * sizeof(float), stream);

    qproj_kernel<<<(NPAR * DH + 255) / 256, 256, 0, stream>>>(xp, wq, bq, qp);
    fused_kernel<<<(NC + 255) / 256, 256, 0, stream>>>(xc, ea, idx, wkv, bkv,
                                                       wkr, bkr, wqr, bqr, qp, s, out);
    norm_kernel<<<(NPAR * DIM + 255) / 256, 256, 0, stream>>>(s, out);
}

// Round 2
// 2274.629 us; speedup vs baseline: 1.7296x; 1.7296x over previous
//
#include <hip/hip_runtime.h>
#include <hip/hip_fp16.h>

#define NC    1000000
#define NPAR  100000
#define DIM   64
#define H     4
#define DQK   8
#define DH    32
#define RPE   9
#define KVDIM 96
#define SCALE 0.35355339059327373f  // DQK^-0.5

// ---------------------------------------------------------------------------
// Kernel A: qp[p][o] = SCALE * (x_parent[p] . wq[:,o] + bq[o])
// ---------------------------------------------------------------------------
__global__ void qproj_kernel(const float* __restrict__ xp,
                             const float* __restrict__ wq,
                             const float* __restrict__ bq,
                             float* __restrict__ qp) {
    int t = blockIdx.x * 256 + threadIdx.x;
    if (t >= NPAR * DH) return;
    int p = t >> 5, o = t & 31;
    const float* xr = xp + (size_t)p * DIM;
    float acc = bq[o];
#pragma unroll
    for (int j = 0; j < DIM; ++j) acc += xr[j] * wq[j * DH + o];
    qp[t] = acc * SCALE;
}

// ---------------------------------------------------------------------------
// Kernel B1: per-parent child counting + within-parent rank.
// Only 1M int atomics (vs 68M fp32 before).
// ---------------------------------------------------------------------------
__global__ void rank_kernel(const int* __restrict__ index,
                            int* __restrict__ cnt,
                            int* __restrict__ rank) {
    int c = blockIdx.x * 256 + threadIdx.x;
    if (c >= NC) return;
    rank[c] = atomicAdd(&cnt[index[c]], 1);
}

// ---------------------------------------------------------------------------
// Kernel B2: single-block exclusive scan of cnt[NPAR] -> rowStart[NPAR+1].
// 1024 threads, each owns a 98-element chunk; Hillis-Steele scan of totals.
// ---------------------------------------------------------------------------
__global__ void scan_kernel(const int* __restrict__ cnt,
                            int* __restrict__ rowStart) {
    __shared__ int sums[1024];
    const int CH = (NPAR + 1023) / 1024;   // 98
    int t = threadIdx.x;
    int base = t * CH;
    int local = 0;
    for (int i = 0; i < CH; ++i) {
        int idx = base + i;
        if (idx < NPAR) local += cnt[idx];
    }
    sums[t] = local;
    __syncthreads();
    for (int off = 1; off < 1024; off <<= 1) {
        int v = sums[t];
        int add = (t >= off) ? sums[t - off] : 0;
        __syncthreads();
        sums[t] = v + add;
        __syncthreads();
    }
    int run = (t > 0) ? sums[t - 1] : 0;   // exclusive prefix of chunk totals
    for (int i = 0; i < CH; ++i) {
        int idx = base + i;
        if (idx < NPAR) { rowStart[idx] = run; run += cnt[idx]; }
    }
    if (t == 1023) rowStart[NPAR] = run;   // == NC
}

// ---------------------------------------------------------------------------
// Kernel B3: atomic-free scatter: order[rowStart[p] + rank[c]] = c
// ---------------------------------------------------------------------------
__global__ void scatter_kernel(const int* __restrict__ index,
                               const int* __restrict__ rank,
                               const int* __restrict__ rowStart,
                               int* __restrict__ order) {
    int c = blockIdx.x * 256 + threadIdx.x;
    if (c >= NC) return;
    order[rowStart[index[c]] + rank[c]] = c;
}

// ---------------------------------------------------------------------------
// Kernel C: fused per-child projection pass (original order, coalesced).
// Writes wv[c][d] = e_{d/16} * v_d (fp16) and ebuf[c][h] = e_h (fp16).
// No atomics.
// ---------------------------------------------------------------------------
__global__ void fused_kernel(const float* __restrict__ xc,
                             const float* __restrict__ ea_g,
                             const int*   __restrict__ index,
                             const float* __restrict__ wkv,
                             const float* __restrict__ bkv,
                             const float* __restrict__ wkr,
                             const float* __restrict__ bkr,
                             const float* __restrict__ wqr,
                             const float* __restrict__ bqr,
                             const float* __restrict__ qp,
                             __half* __restrict__ wv,
                             __half* __restrict__ ebuf) {
    __shared__ float lds[6880];
    float* wkT  = lds;           // [32][64] : wkT[o*64+j] = wkv[j][o]
    float* wvT  = lds + 2048;    // [64][64] : wvT[d*64+j] = wkv[j][32+d]
    float* wkrT = lds + 6144;    // [32][9]
    float* wqrT = lds + 6432;    // [32][9]
    float* bkvL = lds + 6720;    // [96]
    float* bkrL = lds + 6816;    // [32]
    float* bqrL = lds + 6848;    // [32]

    int tid = threadIdx.x;
    for (int i = tid; i < 2048; i += 256) { int o = i >> 6, j = i & 63; wkT[i] = wkv[j * KVDIM + o]; }
    for (int i = tid; i < 4096; i += 256) { int d = i >> 6, j = i & 63; wvT[i] = wkv[j * KVDIM + DH + d]; }
    for (int i = tid; i < 288;  i += 256) { int o = i / 9, r = i - o * 9; wkrT[i] = wkr[r * DH + o]; }
    for (int i = tid; i < 288;  i += 256) { int o = i / 9, r = i - o * 9; wqrT[i] = wqr[r * DH + o]; }
    if (tid < 96) bkvL[tid] = bkv[tid];
    if (tid < 32) { bkrL[tid] = bkr[tid]; bqrL[tid] = bqr[tid]; }
    __syncthreads();

    int c = blockIdx.x * 256 + tid;
    if (c >= NC) return;

    int p = index[c];

    float4 x4[16];
    const float4* xr = (const float4*)(xc + (size_t)c * DIM);
#pragma unroll
    for (int i = 0; i < 16; ++i) x4[i] = xr[i];

    float ea[RPE];
    const float* er = ea_g + (size_t)c * RPE;
#pragma unroll
    for (int r = 0; r < RPE; ++r) ea[r] = er[r];

    const float* qpr = qp + (size_t)p * DH;
    float ev[H];

    // ---- phase 1: compat + e per head ----
#pragma unroll
    for (int h = 0; h < H; ++h) {
        float compat = 0.f;
#pragma unroll 1
        for (int d = 0; d < DQK; ++d) {
            int o = h * DQK + d;
            float k = bkvL[o] + bkrL[o];
            const float4* wk4 = (const float4*)(wkT + o * 64);
#pragma unroll
            for (int j = 0; j < 16; ++j) {
                float4 w = wk4[j]; float4 xx = x4[j];
                k += xx.x * w.x + xx.y * w.y + xx.z * w.z + xx.w * w.w;
            }
            float q = qpr[o] + bqrL[o];
#pragma unroll
            for (int r = 0; r < RPE; ++r) {
                q += ea[r] * wqrT[o * RPE + r];
                k += ea[r] * wkrT[o * RPE + r];
            }
            compat += q * k;
        }
        ev[h] = __expf(compat);
    }
    {
        __half2 e01 = __floats2half2_rn(ev[0], ev[1]);
        __half2 e23 = __floats2half2_rn(ev[2], ev[3]);
        uint2 pk;
        pk.x = *(unsigned int*)&e01;
        pk.y = *(unsigned int*)&e23;
        *(uint2*)(ebuf + (size_t)c * 4) = pk;   // 8B coalesced
    }

    // ---- phase 2: v projection, weighted, fp16 store (coalesced per lane) ----
#pragma unroll
    for (int h = 0; h < H; ++h) {
        float eh = ev[h];
        float vv[16];
#pragma unroll 1
        for (int dd = 0; dd < 16; ++dd) {
            int d = h * 16 + dd;
            float v = bkvL[DH + d];
            const float4* wv4 = (const float4*)(wvT + d * 64);
#pragma unroll
            for (int j = 0; j < 16; ++j) {
                float4 w = wv4[j]; float4 xx = x4[j];
                v += xx.x * w.x + xx.y * w.y + xx.z * w.z + xx.w * w.w;
            }
            vv[dd] = v * eh;
        }
        __half2 h2[8];
#pragma unroll
        for (int i = 0; i < 8; ++i) h2[i] = __floats2half2_rn(vv[2 * i], vv[2 * i + 1]);
        uint4* dst = (uint4*)(wv + (size_t)c * 64 + h * 16);  // 32B per head, 16B aligned
        dst[0] = *(uint4*)&h2[0];
        dst[1] = *(uint4*)&h2[4];
    }
}

// ---------------------------------------------------------------------------
// Kernel D: segmented reduce. One wave per parent; lane = output dim.
// out[p][d] = sum_children wv[cid][d] / (sum_children e[cid][d/16] + 1e-16)
// ---------------------------------------------------------------------------
__global__ void reduce_kernel(const int* __restrict__ rowStart,
                              const int* __restrict__ order,
                              const __half* __restrict__ wv,
                              const __half* __restrict__ ebuf,
                              float* __restrict__ out) {
    int tid = threadIdx.x;
    int p = blockIdx.x * 4 + (tid >> 6);
    int lane = tid & 63;
    int s0 = rowStart[p];
    int s1 = rowStart[p + 1];
    float acc = 0.f, es = 0.f;
    for (int i = s0; i < s1; ++i) {
        int cid = order[i];
        acc += __half2float(wv[(size_t)cid * 64 + lane]);
        es  += __half2float(ebuf[(size_t)cid * 4 + (lane >> 4)]);
    }
    out[(size_t)p * DIM + lane] = acc / (es + 1e-16f);
}

// ---------------------------------------------------------------------------
extern "C" void kernel_launch(void* const* d_in, const int* in_sizes, int n_in,
                              void* d_out, int out_size, void* d_ws, size_t ws_size,
                              hipStream_t stream) {
    const float* xc   = (const float*)d_in[0];
    const float* xp   = (const float*)d_in[1];
    const int*   idx  = (const int*)d_in[2];
    const float* ea   = (const float*)d_in[3];
    const float* wq   = (const float*)d_in[4];
    const float* bq   = (const float*)d_in[5];
    const float* wkv  = (const float*)d_in[6];
    const float* bkv  = (const float*)d_in[7];
    const float* wkr  = (const float*)d_in[8];
    const float* bkr  = (const float*)d_in[9];
    const float* wqr  = (const float*)d_in[10];
    const float* bqr  = (const float*)d_in[11];
    float* out = (float*)d_out;

    // workspace layout (256B-aligned regions)
    char* base = (char*)d_ws;
    size_t off = 0;
    auto alloc = [&](size_t bytes) {
        void* r = base + off;
        off += (bytes + 255) & ~(size_t)255;
        return r;
    };
    float*  qp       = (float*) alloc((size_t)NPAR * DH * sizeof(float));   // 12.8 MB
    int*    cnt      = (int*)   alloc((size_t)NPAR * sizeof(int));          // 0.4 MB
    int*    rowStart = (int*)   alloc(((size_t)NPAR + 1) * sizeof(int));    // 0.4 MB
    int*    rank     = (int*)   alloc((size_t)NC * sizeof(int));            // 4 MB
    int*    order    = (int*)   alloc((size_t)NC * sizeof(int));            // 4 MB
    __half* ebuf     = (__half*)alloc((size_t)NC * H * sizeof(__half));     // 8 MB
    __half* wv       = (__half*)alloc((size_t)NC * DIM * sizeof(__half));   // 128 MB
    (void)ws_size;

    hipMemsetAsync(cnt, 0, (size_t)NPAR * sizeof(int), stream);

    qproj_kernel  <<<(NPAR * DH + 255) / 256, 256, 0, stream>>>(xp, wq, bq, qp);
    rank_kernel   <<<(NC + 255) / 256,        256, 0, stream>>>(idx, cnt, rank);
    scan_kernel   <<<1,                      1024, 0, stream>>>(cnt, rowStart);
    scatter_kernel<<<(NC + 255) / 256,        256, 0, stream>>>(idx, rank, rowStart, order);
    fused_kernel  <<<(NC + 255) / 256,        256, 0, stream>>>(xc, ea, idx, wkv, bkv,
                                                                wkr, bkr, wqr, bqr, qp,
                                                                wv, ebuf);
    reduce_kernel <<<NPAR / 4,                256, 0, stream>>>(rowStart, order, wv, ebuf, out);
}

// Round 3
// 1140.397 us; speedup vs baseline: 3.4498x; 1.9946x over previous
//
#include <hip/hip_runtime.h>
#include <hip/hip_fp16.h>

#define NC    1000000
#define NPAR  100000
#define DIM   64
#define H     4
#define DQK   8
#define DH    32
#define RPE   9
#define KVDIM 96
#define SCALE 0.35355339059327373f  // DQK^-0.5

// ---------------------------------------------------------------------------
// Kernel A: qp[p][o] = SCALE * (x_parent[p] . wq[:,o] + bq[o])
// ---------------------------------------------------------------------------
__global__ __launch_bounds__(256) void qproj_kernel(const float* __restrict__ xp,
                             const float* __restrict__ wq,
                             const float* __restrict__ bq,
                             float* __restrict__ qp) {
    int t = blockIdx.x * 256 + threadIdx.x;
    if (t >= NPAR * DH) return;
    int p = t >> 5, o = t & 31;
    const float* xr = xp + (size_t)p * DIM;
    float acc = bq[o];
#pragma unroll
    for (int j = 0; j < DIM; ++j) acc += xr[j] * wq[j * DH + o];
    qp[t] = acc * SCALE;
}

// ---------------------------------------------------------------------------
// Kernel B1: per-parent child count + within-parent rank (1M int atomics).
// ---------------------------------------------------------------------------
__global__ __launch_bounds__(256) void rank_kernel(const int* __restrict__ index,
                            int* __restrict__ cnt,
                            int* __restrict__ rank) {
    int c = blockIdx.x * 256 + threadIdx.x;
    if (c >= NC) return;
    rank[c] = atomicAdd(&cnt[index[c]], 1);
}

// ---------------------------------------------------------------------------
// Kernel B2: single-block exclusive scan of cnt[NPAR] -> rowStart[NPAR+1].
// ---------------------------------------------------------------------------
__global__ __launch_bounds__(1024) void scan_kernel(const int* __restrict__ cnt,
                            int* __restrict__ rowStart) {
    __shared__ int sums[1024];
    const int CH = (NPAR + 1023) / 1024;   // 98
    int t = threadIdx.x;
    int base = t * CH;
    int local = 0;
    for (int i = 0; i < CH; ++i) {
        int idx = base + i;
        if (idx < NPAR) local += cnt[idx];
    }
    sums[t] = local;
    __syncthreads();
    for (int off = 1; off < 1024; off <<= 1) {
        int v = sums[t];
        int add = (t >= off) ? sums[t - off] : 0;
        __syncthreads();
        sums[t] = v + add;
        __syncthreads();
    }
    int run = (t > 0) ? sums[t - 1] : 0;
    for (int i = 0; i < CH; ++i) {
        int idx = base + i;
        if (idx < NPAR) { rowStart[idx] = run; run += cnt[idx]; }
    }
    if (t == 1023) rowStart[NPAR] = run;   // == NC
}

// ---------------------------------------------------------------------------
// Kernel B3: atomic-free scatter: order[rowStart[p] + rank[c]] = c
// ---------------------------------------------------------------------------
__global__ __launch_bounds__(256) void scatter_kernel(const int* __restrict__ index,
                               const int* __restrict__ rank,
                               const int* __restrict__ rowStart,
                               int* __restrict__ order) {
    int c = blockIdx.x * 256 + threadIdx.x;
    if (c >= NC) return;
    order[rowStart[index[c]] + rank[c]] = c;
}

// ---------------------------------------------------------------------------
// Kernel C: fused per-child pass in PARENT-SORTED order (g = sorted slot).
//  - x/ea reads: per-lane row-contiguous (full cacheline use)
//  - qp gather: siblings adjacent -> L1 broadcast
//  - wv stored chunked [H][NC][16] fp16 via 2KB/wave LDS bounce ->
//    every global store instruction writes a full contiguous 1KB region.
//  - ebuf[g][4] fp16, 8B/lane coalesced.
// ---------------------------------------------------------------------------
__global__ __launch_bounds__(256) void fused_kernel(const float* __restrict__ xc,
                             const float* __restrict__ ea_g,
                             const int*   __restrict__ index,
                             const int*   __restrict__ order,
                             const float* __restrict__ wkv,
                             const float* __restrict__ bkv,
                             const float* __restrict__ wkr,
                             const float* __restrict__ bkr,
                             const float* __restrict__ wqr,
                             const float* __restrict__ bqr,
                             const float* __restrict__ qp,
                             __half* __restrict__ wv,
                             __half* __restrict__ ebuf) {
    __shared__ float lds[6880];
    __shared__ __align__(16) unsigned int stage[4 * 512];  // 2KB per wave
    float* wkT  = lds;           // [32][64] : wkT[o*64+j] = wkv[j][o]
    float* wvT  = lds + 2048;    // [64][64] : wvT[d*64+j] = wkv[j][32+d]
    float* wkrT = lds + 6144;    // [32][9]
    float* wqrT = lds + 6432;    // [32][9]
    float* bkvL = lds + 6720;    // [96]
    float* bkrL = lds + 6816;    // [32]
    float* bqrL = lds + 6848;    // [32]

    int tid = threadIdx.x;
    for (int i = tid; i < 2048; i += 256) { int o = i >> 6, j = i & 63; wkT[i] = wkv[j * KVDIM + o]; }
    for (int i = tid; i < 4096; i += 256) { int d = i >> 6, j = i & 63; wvT[i] = wkv[j * KVDIM + DH + d]; }
    for (int i = tid; i < 288;  i += 256) { int o = i / 9, r = i - o * 9; wkrT[i] = wkr[r * DH + o]; }
    for (int i = tid; i < 288;  i += 256) { int o = i / 9, r = i - o * 9; wqrT[i] = wqr[r * DH + o]; }
    if (tid < 96) bkvL[tid] = bkv[tid];
    if (tid < 32) { bkrL[tid] = bkr[tid]; bqrL[tid] = bqr[tid]; }
    __syncthreads();

    int g = blockIdx.x * 256 + tid;
    if (g >= NC) return;

    int wave = tid >> 6, lane = tid & 63;
    int wbase = blockIdx.x * 256 + wave * 64;

    int c = order[g];       // child id (scattered, row-contiguous data)
    int p = index[c];       // parent (mostly shared across adjacent lanes)

    float4 x4[16];
    const float4* xr = (const float4*)(xc + (size_t)c * DIM);
#pragma unroll
    for (int i = 0; i < 16; ++i) x4[i] = xr[i];

    float ea[RPE];
    const float* er = ea_g + (size_t)c * RPE;
#pragma unroll
    for (int r = 0; r < RPE; ++r) ea[r] = er[r];

    const float* qpr = qp + (size_t)p * DH;
    float ev[H];

    // ---- phase 1: compat + e per head ----
#pragma unroll
    for (int h = 0; h < H; ++h) {
        float compat = 0.f;
#pragma unroll 1
        for (int d = 0; d < DQK; ++d) {
            int o = h * DQK + d;
            float k = bkvL[o] + bkrL[o];
            const float4* wk4 = (const float4*)(wkT + o * 64);
#pragma unroll
            for (int j = 0; j < 16; ++j) {
                float4 w = wk4[j]; float4 xx = x4[j];
                k += xx.x * w.x + xx.y * w.y + xx.z * w.z + xx.w * w.w;
            }
            float q = qpr[o] + bqrL[o];
#pragma unroll
            for (int r = 0; r < RPE; ++r) {
                q += ea[r] * wqrT[o * RPE + r];
                k += ea[r] * wkrT[o * RPE + r];
            }
            compat += q * k;
        }
        ev[h] = __expf(compat);
    }
    {
        __half2 e01 = __floats2half2_rn(ev[0], ev[1]);
        __half2 e23 = __floats2half2_rn(ev[2], ev[3]);
        uint2 pk;
        pk.x = *(unsigned int*)&e01;
        pk.y = *(unsigned int*)&e23;
        *(uint2*)(ebuf + (size_t)g * 4) = pk;   // 8B/lane, consecutive g -> coalesced
    }

    // ---- phase 2: v projection per head; LDS bounce -> coalesced 1KB stores ----
#pragma unroll
    for (int h = 0; h < H; ++h) {
        float eh = ev[h];
        unsigned int* stw = stage + wave * 512 + lane * 8;
#pragma unroll 1
        for (int dd2 = 0; dd2 < 8; ++dd2) {
            int d0 = h * 16 + 2 * dd2;
            float v0 = bkvL[DH + d0];
            float v1 = bkvL[DH + d0 + 1];
            const float4* w0 = (const float4*)(wvT + d0 * 64);
            const float4* w1 = w0 + 16;
#pragma unroll
            for (int j = 0; j < 16; ++j) {
                float4 a = w0[j]; float4 b = w1[j]; float4 xx = x4[j];
                v0 += xx.x * a.x + xx.y * a.y + xx.z * a.z + xx.w * a.w;
                v1 += xx.x * b.x + xx.y * b.y + xx.z * b.z + xx.w * b.w;
            }
            __half2 hp = __floats2half2_rn(v0 * eh, v1 * eh);
            stw[dd2] = *(unsigned int*)&hp;
        }
        // wave-local readback (no barrier needed; same wave, in-order DS)
        const uint4* sp = (const uint4*)(stage + wave * 512);
        uint4* gdst = (uint4*)(wv + (size_t)h * NC * 16 + (size_t)wbase * 16);
        uint4 t0 = sp[lane];
        uint4 t1 = sp[lane + 64];
        gdst[lane] = t0;
        gdst[lane + 64] = t1;
    }
}

// ---------------------------------------------------------------------------
// Kernel D: segmented reduce over CONTIGUOUS sorted rows. Wave per parent.
// out[p][d] = sum_i wv[d>>4][i][d&15] / (sum_i ebuf[i][d>>4] + 1e-16)
// ---------------------------------------------------------------------------
__global__ __launch_bounds__(256) void reduce_kernel(const int* __restrict__ rowStart,
                              const __half* __restrict__ wv,
                              const __half* __restrict__ ebuf,
                              float* __restrict__ out) {
    int tid = threadIdx.x;
    int p = blockIdx.x * 4 + (tid >> 6);
    int lane = tid & 63;
    int q = lane >> 4, t = lane & 15;
    int s0 = rowStart[p];
    int s1 = rowStart[p + 1];
    const __half* wq_ = wv + (size_t)q * NC * 16 + t;
    float acc = 0.f, es = 0.f;
    for (int i = s0; i < s1; ++i) {
        acc += __half2float(wq_[(size_t)i * 16]);
        es  += __half2float(ebuf[(size_t)i * 4 + q]);
    }
    out[(size_t)p * DIM + lane] = acc / (es + 1e-16f);
}

// ---------------------------------------------------------------------------
extern "C" void kernel_launch(void* const* d_in, const int* in_sizes, int n_in,
                              void* d_out, int out_size, void* d_ws, size_t ws_size,
                              hipStream_t stream) {
    const float* xc   = (const float*)d_in[0];
    const float* xp   = (const float*)d_in[1];
    const int*   idx  = (const int*)d_in[2];
    const float* ea   = (const float*)d_in[3];
    const float* wq   = (const float*)d_in[4];
    const float* bq   = (const float*)d_in[5];
    const float* wkv  = (const float*)d_in[6];
    const float* bkv  = (const float*)d_in[7];
    const float* wkr  = (const float*)d_in[8];
    const float* bkr  = (const float*)d_in[9];
    const float* wqr  = (const float*)d_in[10];
    const float* bqr  = (const float*)d_in[11];
    float* out = (float*)d_out;

    char* base = (char*)d_ws;
    size_t off = 0;
    auto alloc = [&](size_t bytes) {
        void* r = base + off;
        off += (bytes + 255) & ~(size_t)255;
        return r;
    };
    float*  qp       = (float*) alloc((size_t)NPAR * DH * sizeof(float));   // 12.8 MB
    int*    cnt      = (int*)   alloc((size_t)NPAR * sizeof(int));          // 0.4 MB
    int*    rowStart = (int*)   alloc(((size_t)NPAR + 1) * sizeof(int));    // 0.4 MB
    int*    rank     = (int*)   alloc((size_t)NC * sizeof(int));            // 4 MB
    int*    order    = (int*)   alloc((size_t)NC * sizeof(int));            // 4 MB
    __half* ebuf     = (__half*)alloc((size_t)NC * H * sizeof(__half));     // 8 MB
    __half* wv       = (__half*)alloc((size_t)NC * DIM * sizeof(__half));   // 128 MB
    (void)ws_size;

    hipMemsetAsync(cnt, 0, (size_t)NPAR * sizeof(int), stream);

    qproj_kernel  <<<(NPAR * DH + 255) / 256, 256, 0, stream>>>(xp, wq, bq, qp);
    rank_kernel   <<<(NC + 255) / 256,        256, 0, stream>>>(idx, cnt, rank);
    scan_kernel   <<<1,                      1024, 0, stream>>>(cnt, rowStart);
    scatter_kernel<<<(NC + 255) / 256,        256, 0, stream>>>(idx, rank, rowStart, order);
    fused_kernel  <<<(NC + 255) / 256,        256, 0, stream>>>(xc, ea, idx, order, wkv, bkv,
                                                                wkr, bkr, wqr, bqr, qp,
                                                                wv, ebuf);
    reduce_kernel <<<NPAR / 4,                256, 0, stream>>>(rowStart, wv, ebuf, out);
}

// Round 4
// 867.283 us; speedup vs baseline: 4.5362x; 1.3149x over previous
//
#include <hip/hip_runtime.h>

#define NC    1000000
#define NPAR  100000
#define DIM   64
#define H     4
#define RPE   9
#define SCALE 0.35355339059327373f  // DQK^-0.5

typedef __attribute__((ext_vector_type(8))) short short8;   // 8 bf16 (4 VGPRs)
typedef __attribute__((ext_vector_type(4))) float f32x4;    // MFMA C/D frag

__device__ inline unsigned short f2bf(float f) {
    unsigned int u = __float_as_uint(f);
    u += 0x7fff + ((u >> 16) & 1);          // round-to-nearest-even
    return (unsigned short)(u >> 16);
}
__device__ inline unsigned int pack2bf(float a, float b) {
    return (unsigned int)f2bf(a) | ((unsigned int)f2bf(b) << 16);
}

// ---------------------------------------------------------------------------
// Kernel A: qp[p][o] = SCALE*(x_parent[p].wq[:,o] + bq[o]). Thread per parent.
// ---------------------------------------------------------------------------
__global__ __launch_bounds__(256) void qproj_kernel(const float* __restrict__ xp,
                             const float* __restrict__ wq,
                             const float* __restrict__ bq,
                             float* __restrict__ qp) {
    __shared__ float wqT[32 * 64];   // wqT[o*64+j] = wq[j*32+o]
    __shared__ float bqL[32];
    int tid = threadIdx.x;
    for (int i = tid; i < 2048; i += 256) { int o = i >> 6, j = i & 63; wqT[i] = wq[j * 32 + o]; }
    if (tid < 32) bqL[tid] = bq[tid];
    __syncthreads();
    int p = blockIdx.x * 256 + tid;
    if (p >= NPAR) return;
    float4 x4[16];
    const float4* xr = (const float4*)(xp + (size_t)p * 64);
#pragma unroll
    for (int i = 0; i < 16; ++i) x4[i] = xr[i];
    float* qpr = qp + (size_t)p * 32;
#pragma unroll 1
    for (int o = 0; o < 32; ++o) {
        float acc = bqL[o];
        const float4* w4 = (const float4*)(wqT + o * 64);
#pragma unroll
        for (int j = 0; j < 16; ++j) { float4 w = w4[j], xx = x4[j];
            acc += xx.x * w.x + xx.y * w.y + xx.z * w.z + xx.w * w.w; }
        qpr[o] = acc * SCALE;
    }
}

// ---------------------------------------------------------------------------
// Kernel B1: per-parent child count + within-parent rank (1M int atomics).
// ---------------------------------------------------------------------------
__global__ __launch_bounds__(256) void rank_kernel(const int* __restrict__ index,
                            int* __restrict__ cnt, int* __restrict__ rank) {
    int c = blockIdx.x * 256 + threadIdx.x;
    if (c >= NC) return;
    rank[c] = atomicAdd(&cnt[index[c]], 1);
}

// ---------------------------------------------------------------------------
// Kernel B2: single-block exclusive scan cnt[NPAR] -> rowStart[NPAR+1].
// ---------------------------------------------------------------------------
__global__ __launch_bounds__(1024) void scan_kernel(const int* __restrict__ cnt,
                            int* __restrict__ rowStart) {
    __shared__ int sums[1024];
    const int CH = (NPAR + 1023) / 1024;   // 98
    int t = threadIdx.x;
    int base = t * CH;
    int local = 0;
    for (int i = 0; i < CH; ++i) { int idx = base + i; if (idx < NPAR) local += cnt[idx]; }
    sums[t] = local;
    __syncthreads();
    for (int off = 1; off < 1024; off <<= 1) {
        int v = sums[t];
        int add = (t >= off) ? sums[t - off] : 0;
        __syncthreads();
        sums[t] = v + add;
        __syncthreads();
    }
    int run = (t > 0) ? sums[t - 1] : 0;
    for (int i = 0; i < CH; ++i) {
        int idx = base + i;
        if (idx < NPAR) { rowStart[idx] = run; run += cnt[idx]; }
    }
    if (t == 1023) rowStart[NPAR] = run;
}

// ---------------------------------------------------------------------------
// Kernel B3: atomic-free scatter: order[rowStart[p] + rank[c]] = c
// ---------------------------------------------------------------------------
__global__ __launch_bounds__(256) void scatter_kernel(const int* __restrict__ index,
                               const int* __restrict__ rank,
                               const int* __restrict__ rowStart,
                               int* __restrict__ order) {
    int c = blockIdx.x * 256 + threadIdx.x;
    if (c >= NC) return;
    order[rowStart[index[c]] + rank[c]] = c;
}

// ---------------------------------------------------------------------------
// Kernel C: MFMA fused pass. Block = 256 sorted children.
//  GEMM: A(256x96 bf16)=[x|ea|1|0] x B(96x128 bf16)=[k|v|qrpe] via 16x16x32.
//  Epilogue: q.k -> e=exp; scale v by e; block-level segmented reduction
//  (interior parents: plain store; boundary parents: atomicAdd).
// ---------------------------------------------------------------------------
__global__ __launch_bounds__(256, 2) void fused_kernel(
    const float* __restrict__ xc, const float* __restrict__ ea_g,
    const int* __restrict__ index, const int* __restrict__ order,
    const int* __restrict__ rowStart,
    const float* __restrict__ wkv, const float* __restrict__ bkv,
    const float* __restrict__ wkr, const float* __restrict__ bkr,
    const float* __restrict__ wqr, const float* __restrict__ bqr,
    const float* __restrict__ qp,
    float* __restrict__ outw, float* __restrict__ sW)
{
    __shared__ __align__(16) char R1[73728];   // A(48K)+B(24K) -> kqT(65K) -> wvS(68K)
    __shared__ float e_lds[256 * 4];
    __shared__ int par_s[256];
    __shared__ int wcnt[4];
    __shared__ int segStart[258];              // [256]=end cap slot, [257]=nseg

    uint4* A4 = (uint4*)R1;                    // A4[kb*256 + c], kb=0..11 (k-chunk of 8)
    uint4* B4 = (uint4*)(R1 + 49152);          // B4[kb*128 + n]
    float* kqT = (float*)R1;                   // [64][260]: rows 0..31=k, 32..63=qrpe
    float* wvS = (float*)R1;                   // [256][68]: e-scaled v per child

    const int tid  = threadIdx.x;
    const int lane = tid & 63, wave = tid >> 6;
    const int col  = lane & 15, quad = lane >> 4;
    const int G    = blockIdx.x * 256;
    const int validCB = min(NC - G, 256);

    // ---- P1: stage A (one thread = one child row) ----
    {
        const int c = tid;
        const bool valid = c < validCB;
        int ch = 0, p = 0x7fffffff;
        if (valid) { ch = order[G + c]; p = index[ch]; }
        par_s[c] = p;
        float4 xr4[16];
        float ear[9];
        if (valid) {
            const float4* xr = (const float4*)(xc + (size_t)ch * 64);
#pragma unroll
            for (int i = 0; i < 16; ++i) xr4[i] = xr[i];
            const float* er = ea_g + (size_t)ch * 9;
#pragma unroll
            for (int r = 0; r < 9; ++r) ear[r] = er[r];
        } else {
#pragma unroll
            for (int i = 0; i < 16; ++i) xr4[i] = make_float4(0.f, 0.f, 0.f, 0.f);
#pragma unroll
            for (int r = 0; r < 9; ++r) ear[r] = 0.f;
        }
#pragma unroll
        for (int kb = 0; kb < 8; ++kb) {
            uint4 v;
            v.x = pack2bf(xr4[kb * 2].x, xr4[kb * 2].y);
            v.y = pack2bf(xr4[kb * 2].z, xr4[kb * 2].w);
            v.z = pack2bf(xr4[kb * 2 + 1].x, xr4[kb * 2 + 1].y);
            v.w = pack2bf(xr4[kb * 2 + 1].z, xr4[kb * 2 + 1].w);
            A4[kb * 256 + c] = v;
        }
        {
            uint4 v;
            v.x = pack2bf(ear[0], ear[1]); v.y = pack2bf(ear[2], ear[3]);
            v.z = pack2bf(ear[4], ear[5]); v.w = pack2bf(ear[6], ear[7]);
            A4[8 * 256 + c] = v;
        }
        {
            uint4 v;
            v.x = pack2bf(ear[8], valid ? 1.f : 0.f);   // bias row k=73
            v.y = 0u; v.z = 0u; v.w = 0u;
            A4[9 * 256 + c] = v;
        }
        uint4 z; z.x = z.y = z.z = z.w = 0u;
        A4[10 * 256 + c] = z;
        A4[11 * 256 + c] = z;
    }

    // ---- P1b: stage B (weights+biases, cooperative) ----
    for (int i = tid; i < 12 * 128; i += 256) {
        int kb = i >> 7, n = i & 127;
        float w[8];
#pragma unroll
        for (int jj = 0; jj < 8; ++jj) {
            int k = kb * 8 + jj;
            float val = 0.f;
            if (n < 32) {                       // k-projection (x + rpe + bias)
                if (k < 64)       val = wkv[k * 96 + n];
                else if (k < 73)  val = wkr[(k - 64) * 32 + n];
                else if (k == 73) val = bkv[n] + bkr[n];
            } else if (n < 96) {                // v-projection
                int d = n - 32;
                if (k < 64)       val = wkv[k * 96 + 32 + d];
                else if (k == 73) val = bkv[32 + d];
            } else {                            // q rpe (+bias)
                int o = n - 96;
                if (k >= 64 && k < 73) val = wqr[(k - 64) * 32 + o];
                else if (k == 73)      val = bqr[o];
            }
            w[jj] = val;
        }
        uint4 v;
        v.x = pack2bf(w[0], w[1]); v.y = pack2bf(w[2], w[3]);
        v.z = pack2bf(w[4], w[5]); v.w = pack2bf(w[6], w[7]);
        B4[kb * 128 + n] = v;
    }
    __syncthreads();

    // ---- P2: MFMA. Wave computes 64 children x 128 outputs ----
    f32x4 acc[4][8];
#pragma unroll
    for (int mt = 0; mt < 4; ++mt)
#pragma unroll
        for (int nt = 0; nt < 8; ++nt) acc[mt][nt] = (f32x4){0.f, 0.f, 0.f, 0.f};
    const int wbase = wave * 64;
#pragma unroll
    for (int ks = 0; ks < 3; ++ks) {
        int kb = ks * 4 + quad;
        short8 af[4], bf[8];
#pragma unroll
        for (int mt = 0; mt < 4; ++mt)
            af[mt] = ((const short8*)A4)[kb * 256 + wbase + mt * 16 + col];
#pragma unroll
        for (int nt = 0; nt < 8; ++nt)
            bf[nt] = ((const short8*)B4)[kb * 128 + nt * 16 + col];
#pragma unroll
        for (int mt = 0; mt < 4; ++mt)
#pragma unroll
            for (int nt = 0; nt < 8; ++nt)
                acc[mt][nt] = __builtin_amdgcn_mfma_f32_16x16x32_bf16(af[mt], bf[nt], acc[mt][nt], 0, 0, 0);
    }
    __syncthreads();   // A/B dead; R1 reused as kqT

    // ---- P3: dump k (n 0..31) and qrpe (n 96..127) frags -> kqT ----
#pragma unroll
    for (int mt = 0; mt < 4; ++mt) {
        int cb = wbase + mt * 16 + quad * 4;
#pragma unroll
        for (int nt = 0; nt < 2; ++nt) {
            int nl = nt * 16 + col;
            *(f32x4*)(kqT + nl * 260 + cb) = acc[mt][nt];
        }
#pragma unroll
        for (int nt = 6; nt < 8; ++nt) {
            int nl = 32 + (nt - 6) * 16 + col;
            *(f32x4*)(kqT + nl * 260 + cb) = acc[mt][nt];
        }
    }
    __syncthreads();

    // ---- P4: glue (thread = child): compat -> e; segment-head list ----
    {
        const int c = tid;
        bool valid = c < validCB;
        int p = par_s[c];
        float e0 = 0.f, e1 = 0.f, e2 = 0.f, e3 = 0.f;
        if (valid) {
            const float* qpr = qp + (size_t)p * 32;
            float qv[32];
#pragma unroll
            for (int i = 0; i < 8; ++i) *(float4*)(qv + 4 * i) = ((const float4*)qpr)[i];
            float comp[4] = {0.f, 0.f, 0.f, 0.f};
#pragma unroll
            for (int o = 0; o < 32; ++o) {
                float kk = kqT[o * 260 + c];
                float qq = qv[o] + kqT[(32 + o) * 260 + c];
                comp[o >> 3] += qq * kk;
            }
            e0 = __expf(comp[0]); e1 = __expf(comp[1]);
            e2 = __expf(comp[2]); e3 = __expf(comp[3]);
        }
        *(float4*)(e_lds + c * 4) = make_float4(e0, e1, e2, e3);

        bool ishead = valid && (c == 0 || par_s[c - 1] != p);
        unsigned long long mask = __ballot(ishead);
        if (lane == 0) wcnt[wave] = __popcll(mask);
        __syncthreads();   // kqT reads done; e_lds/wcnt published
        int base = 0;
#pragma unroll
        for (int w = 0; w < 4; ++w) if (w < wave) base += wcnt[w];
        if (ishead) segStart[base + __popcll(mask & ((1ull << lane) - 1))] = c;
        if (tid == 0) {
            int ns = wcnt[0] + wcnt[1] + wcnt[2] + wcnt[3];
            segStart[ns] = validCB;
            segStart[257] = ns;
        }
    }

    // ---- P5: scale v frags by e -> wvS (overwrites kqT region) ----
#pragma unroll
    for (int mt = 0; mt < 4; ++mt) {
        int cb = wbase + mt * 16 + quad * 4;
#pragma unroll
        for (int nt = 2; nt < 6; ++nt) {
            int d = (nt - 2) * 16 + col;
            int h = nt - 2;
#pragma unroll
            for (int r = 0; r < 4; ++r) {
                float e = e_lds[(cb + r) * 4 + h];
                wvS[(cb + r) * 68 + d] = acc[mt][nt][r] * e;
            }
        }
    }
    __syncthreads();

    // ---- P6: segmented reduce. Wave per segment (lane = dim). ----
    {
        int nseg = segStart[257];
        for (int s = wave; s < nseg; s += 4) {
            int a = segStart[s], b = segStart[s + 1];
            int p = par_s[a];
            int d = lane, h = lane >> 4;
            float vs = 0.f, es = 0.f;
            for (int c2 = a; c2 < b; ++c2) {
                vs += wvS[c2 * 68 + d];
                es += e_lds[c2 * 4 + h];
            }
            bool full = (rowStart[p] == G + a) && (rowStart[p + 1] == G + b);
            if (full) {
                outw[(size_t)p * 64 + d] = vs;
                if ((d & 15) == 0) sW[(size_t)p * 4 + h] = es;
            } else {
                atomicAdd(&outw[(size_t)p * 64 + d], vs);
                if ((d & 15) == 0) atomicAdd(&sW[(size_t)p * 4 + h], es);
            }
        }
    }
}

// ---------------------------------------------------------------------------
// Kernel E: out[p][d] /= (s[p][d/16] + 1e-16)
// ---------------------------------------------------------------------------
__global__ __launch_bounds__(256) void norm_kernel(const float* __restrict__ sW,
                                                   float* __restrict__ out) {
    int t = blockIdx.x * 256 + threadIdx.x;
    if (t >= NPAR * 64) return;
    out[t] = out[t] / (sW[(t >> 6) * 4 + ((t >> 4) & 3)] + 1e-16f);
}

// ---------------------------------------------------------------------------
extern "C" void kernel_launch(void* const* d_in, const int* in_sizes, int n_in,
                              void* d_out, int out_size, void* d_ws, size_t ws_size,
                              hipStream_t stream) {
    const float* xc   = (const float*)d_in[0];
    const float* xp   = (const float*)d_in[1];
    const int*   idx  = (const int*)d_in[2];
    const float* ea   = (const float*)d_in[3];
    const float* wq   = (const float*)d_in[4];
    const float* bq   = (const float*)d_in[5];
    const float* wkv  = (const float*)d_in[6];
    const float* bkv  = (const float*)d_in[7];
    const float* wkr  = (const float*)d_in[8];
    const float* bkr  = (const float*)d_in[9];
    const float* wqr  = (const float*)d_in[10];
    const float* bqr  = (const float*)d_in[11];
    float* out = (float*)d_out;

    char* base = (char*)d_ws;
    size_t off = 0;
    auto alloc = [&](size_t bytes) {
        void* r = base + off;
        off += (bytes + 255) & ~(size_t)255;
        return r;
    };
    float* qp       = (float*)alloc((size_t)NPAR * 32 * sizeof(float));   // 12.8 MB
    int*   cnt      = (int*)  alloc((size_t)NPAR * sizeof(int));
    int*   rowStart = (int*)  alloc(((size_t)NPAR + 1) * sizeof(int));
    int*   rank     = (int*)  alloc((size_t)NC * sizeof(int));            // 4 MB
    int*   order    = (int*)  alloc((size_t)NC * sizeof(int));            // 4 MB
    float* sW       = (float*)alloc((size_t)NPAR * 4 * sizeof(float));    // 1.6 MB
    (void)ws_size;

    hipMemsetAsync(cnt, 0, (size_t)NPAR * sizeof(int), stream);
    hipMemsetAsync(sW,  0, (size_t)NPAR * 4 * sizeof(float), stream);
    hipMemsetAsync(out, 0, (size_t)NPAR * 64 * sizeof(float), stream);

    qproj_kernel  <<<(NPAR + 255) / 256, 256, 0, stream>>>(xp, wq, bq, qp);
    rank_kernel   <<<(NC + 255) / 256,   256, 0, stream>>>(idx, cnt, rank);
    scan_kernel   <<<1,                 1024, 0, stream>>>(cnt, rowStart);
    scatter_kernel<<<(NC + 255) / 256,   256, 0, stream>>>(idx, rank, rowStart, order);
    fused_kernel  <<<(NC + 255) / 256,   256, 0, stream>>>(xc, ea, idx, order, rowStart,
                                                           wkv, bkv, wkr, bkr, wqr, bqr,
                                                           qp, out, sW);
    norm_kernel   <<<(NPAR * 64 + 255) / 256, 256, 0, stream>>>(sW, out);
}